// Round 7
// baseline (250.748 us; speedup 1.0000x reference)
//
#include <hip/hip_runtime.h>

#define N_NODES 40000
#define N_EDGES 640000
#define DIM 128
#define PAD 64            // deg ~ Poisson(16), P(>64) ~ 1e-18
#define NBLK_MSG 313      // ceil(40000/128): 4 waves/block, 32 rows/wave
#define FAT_BLOCKS (NBLK_MSG * 9)   // bx%9==0 -> msg role (313), else scatter (2504)

typedef __bf16 bf16;
typedef __bf16 v8bf __attribute__((ext_vector_type(8)));
typedef float f32x4 __attribute__((ext_vector_type(4)));

#define MFMA(a, b, c) __builtin_amdgcn_mfma_f32_16x16x32_bf16(a, b, c, 0, 0, 0)

// ---------------------------------------------------------------------------
// Per-block redundant dtype detection (8 KB of L2-hot reads, no global
// round-trip). f32 low halfwords are random mantissa bits (exp>=0xC0 w.p. 25%
// per sample); bf16 activations never reach exp 0x83. int64 indices < 40000
// have all-zero high words.
// ---------------------------------------------------------------------------
__device__ __forceinline__ void detect(const void* x, const void* ei,
                                       int* sf, int& f32m, int& i64m) {
    const int tid = threadIdx.x;
    if (tid == 0) { sf[0] = 0; sf[1] = 0; }
    __syncthreads();
    const unsigned short* xh = (const unsigned short*)x;
    const unsigned int* eiw = (const unsigned int*)ei;
    int isf32 = 0; unsigned int orhi = 0;
    #pragma unroll
    for (int j = 0; j < 4; ++j) {
        unsigned short h = xh[2 * (tid + 256 * j)];
        if (((h >> 7) & 0xFF) >= 0xC0) isf32 = 1;
        orhi |= eiw[2 * (tid + 256 * j) + 1];
    }
    if (isf32) atomicOr(&sf[0], 1);
    if (orhi)  atomicOr(&sf[1], 1);
    __syncthreads();
    f32m = sf[0];
    i64m = sf[1] ? 0 : 1;
}

// load 8 consecutive "float" elements as bf16 fragment (cvt in reg if f32)
template<bool F32>
__device__ __forceinline__ v8bf ld8(const void* p, size_t idx) {
    if constexpr (F32) {
        const float* f = (const float*)p + idx;
        float4 a = *(const float4*)f, b = *(const float4*)(f + 4);
        v8bf r;
        r[0] = (bf16)a.x; r[1] = (bf16)a.y; r[2] = (bf16)a.z; r[3] = (bf16)a.w;
        r[4] = (bf16)b.x; r[5] = (bf16)b.y; r[6] = (bf16)b.z; r[7] = (bf16)b.w;
        return r;
    } else {
        return *(const v8bf*)((const bf16*)p + idx);
    }
}

template<bool F32>
__device__ __forceinline__ float lds1(const void* p, size_t i) {
    if constexpr (F32) return ((const float*)p)[i];
    else               return (float)((const bf16*)p)[i];
}

// ---------------------------------------------------------------------------
// msg role: y = relu(x@Wm1^T+bm1)@Wm2^T+bm2 for 128 rows/block. Per-wave
// LDS-free GEMM: A/B fragments straight from global (L2-resident weights),
// f32->bf16 in registers; 8 KB/wave XOR-swizzled scratch for the h1
// C-layout -> A-layout transpose (2-way max bank aliasing = free):
//   off(row,col) = row*128 + (((col>>3) ^ (row&15))<<3) + (col&7)
// ---------------------------------------------------------------------------
template<bool F32>
__device__ void msg_body(const void* x, const void* Wm1, const void* bm1,
                         const void* Wm2, const void* bm2,
                         bf16* __restrict__ y, bf16* s, int mb) {
    const int wave = threadIdx.x >> 6, lane = threadIdx.x & 63;
    const int l15 = lane & 15, quad = lane >> 4;
    const int row0 = (mb * 4 + wave) * 32;
    const int ra = min(row0 + l15, N_NODES - 1);
    const int rb = min(row0 + 16 + l15, N_NODES - 1);

    // layer 1
    f32x4 acc[2][8] = {};
    #pragma unroll
    for (int kt = 0; kt < 4; ++kt) {
        int k0 = kt * 32 + quad * 8;
        v8bf a0 = ld8<F32>(x, (size_t)ra * DIM + k0);
        v8bf a1 = ld8<F32>(x, (size_t)rb * DIM + k0);
        #pragma unroll
        for (int ct = 0; ct < 8; ++ct) {
            v8bf b = ld8<F32>(Wm1, (size_t)(ct * 16 + l15) * DIM + k0);
            acc[0][ct] = MFMA(a0, b, acc[0][ct]);
            acc[1][ct] = MFMA(a1, b, acc[1][ct]);
        }
    }
    // relu + bias -> swizzled scratch (wave-local; no barrier)
    #pragma unroll
    for (int ct = 0; ct < 8; ++ct) {
        float bb = lds1<F32>(bm1, ct * 16 + l15);
        int c8w = (ct << 1) | (l15 >> 3);
        #pragma unroll
        for (int i = 0; i < 2; ++i)
            #pragma unroll
            for (int r = 0; r < 4; ++r) {
                int row = i * 16 + quad * 4 + r;
                s[row * DIM + (((c8w ^ (row & 15)) << 3) | (l15 & 7))] =
                    (bf16)fmaxf(acc[i][ct][r] + bb, 0.f);
            }
    }
    // layer 2
    f32x4 acc2[2][8] = {};
    #pragma unroll
    for (int kt = 0; kt < 4; ++kt) {
        int k0 = kt * 32 + quad * 8;
        int c8 = kt * 4 + quad;
        v8bf a0 = *(const v8bf*)&s[l15 * DIM + ((c8 ^ l15) << 3)];
        v8bf a1 = *(const v8bf*)&s[(16 + l15) * DIM + ((c8 ^ l15) << 3)];
        #pragma unroll
        for (int ct = 0; ct < 8; ++ct) {
            v8bf b = ld8<F32>(Wm2, (size_t)(ct * 16 + l15) * DIM + k0);
            acc2[0][ct] = MFMA(a0, b, acc2[0][ct]);
            acc2[1][ct] = MFMA(a1, b, acc2[1][ct]);
        }
    }
    #pragma unroll
    for (int ct = 0; ct < 8; ++ct) {
        float bb = lds1<F32>(bm2, ct * 16 + l15);
        #pragma unroll
        for (int i = 0; i < 2; ++i)
            #pragma unroll
            for (int r = 0; r < 4; ++r) {
                int grow = row0 + i * 16 + quad * 4 + r;
                if (grow < N_NODES)
                    y[(size_t)grow * DIM + ct * 16 + l15] = (bf16)(acc2[i][ct][r] + bb);
            }
    }
}

// ---------------------------------------------------------------------------
// Fat kernel: msg (MFMA-heavy) and edge scatter (latency-bound) co-scheduled.
// bx%9==0 -> msg block; else scatter block (256 edges each, u16 bucket write).
// ---------------------------------------------------------------------------
__global__ __launch_bounds__(256) void fat_kernel(
    const void* __restrict__ x, const void* __restrict__ ei,
    const void* Wm1, const void* bm1, const void* Wm2, const void* bm2,
    int* __restrict__ cnt, unsigned short* __restrict__ padded,
    bf16* __restrict__ y)
{
    __shared__ __align__(16) bf16 sc[4][32 * DIM];   // 32 KB (msg role)
    __shared__ int sf[2];
    int f32m, i64m;
    detect(x, ei, sf, f32m, i64m);

    const int bx = blockIdx.x;
    if (bx % 9 == 0) {
        int mb = bx / 9;
        if (f32m) msg_body<true>(x, Wm1, bm1, Wm2, bm2, y, sc[threadIdx.x >> 6], mb);
        else      msg_body<false>(x, Wm1, bm1, Wm2, bm2, y, sc[threadIdx.x >> 6], mb);
    } else {
        int sb = bx - bx / 9 - 1;                    // 0..2503
        int e = sb * 256 + threadIdx.x;
        if (e < N_EDGES) {
            int s, d;
            if (i64m) {
                const long long* p = (const long long*)ei;
                s = (int)p[e]; d = (int)p[N_EDGES + e];
            } else {
                const int* p = (const int*)ei;
                s = p[e]; d = p[N_EDGES + e];
            }
            int pos = atomicAdd(&cnt[d], 1);
            if (pos < PAD) padded[(d << 6) + pos] = (unsigned short)s;
        }
    }
}

// ---------------------------------------------------------------------------
// Per-node gather-mean over padded u16 buckets, wave-per-node; 4 slots x
// dual stream = 8 row-loads in flight per wave iteration.
// ---------------------------------------------------------------------------
__device__ __forceinline__ void accum8(float* s, uint4 v) {
    v8bf b = __builtin_bit_cast(v8bf, v);
    #pragma unroll
    for (int j = 0; j < 8; ++j) s[j] += (float)b[j];
}

__global__ __launch_bounds__(256) void agg_kernel(const bf16* __restrict__ y,
                                                  const unsigned short* __restrict__ padded,
                                                  const int* __restrict__ cnt,
                                                  bf16* __restrict__ agg) {
    const int node = (blockIdx.x << 2) + (threadIdx.x >> 6);
    const int lane = threadIdx.x & 63;
    const int slot = lane >> 4, c16 = lane & 15;
    const int c = min(cnt[node], PAD);
    const int beg = node << 6;
    const int end = beg + c;
    const uint4* yv = (const uint4*)y;

    float s0[8] = {}, s1[8] = {};
    int e = beg + slot;
    for (; e + 4 < end; e += 8) {
        int i0 = padded[e], i1 = padded[e + 4];
        uint4 v0 = yv[(size_t)i0 * 16 + c16];
        uint4 v1 = yv[(size_t)i1 * 16 + c16];
        accum8(s0, v0);
        accum8(s1, v1);
    }
    if (e < end) accum8(s0, yv[(size_t)padded[e] * 16 + c16]);

    float inv = 1.f / (float)(c > 0 ? c : 1);
    v8bf o;
    #pragma unroll
    for (int j = 0; j < 8; ++j) {
        float v = s0[j] + s1[j];
        v += __shfl_xor(v, 16);
        v += __shfl_xor(v, 32);
        o[j] = (bf16)(v * inv);
    }
    if (slot == 0)
        ((uint4*)agg)[(size_t)node * 16 + c16] = __builtin_bit_cast(uint4, o);
}

// ---------------------------------------------------------------------------
// update: u = relu([x|agg]@Wu1^T+bu1)@Wu2^T+bu2; h=u+x; LN(h)*gamma+beta.
// Direct global reads (f32 cvt in reg); LN via 16-lane quad shuffle reduce.
// ---------------------------------------------------------------------------
template<bool F32>
__device__ void update_body(const void* x, const bf16* __restrict__ agg,
                            const void* Wu1, const void* bu1,
                            const void* Wu2, const void* bu2,
                            const void* gam, const void* bet,
                            void* __restrict__ out, bf16* s, int ub) {
    const int wave = threadIdx.x >> 6, lane = threadIdx.x & 63;
    const int l15 = lane & 15, quad = lane >> 4;
    const int row0 = (ub * 4 + wave) * 32;
    const int ra = min(row0 + l15, N_NODES - 1);
    const int rb = min(row0 + 16 + l15, N_NODES - 1);

    // layer 1: K = 256 over [x | agg]
    f32x4 acc[2][8] = {};
    #pragma unroll
    for (int kt = 0; kt < 8; ++kt) {
        int k0 = kt * 32 + quad * 8;
        v8bf a0, a1;
        if (kt < 4) {
            a0 = ld8<F32>(x, (size_t)ra * DIM + k0);
            a1 = ld8<F32>(x, (size_t)rb * DIM + k0);
        } else {
            a0 = *(const v8bf*)&agg[(size_t)ra * DIM + (k0 - 128)];
            a1 = *(const v8bf*)&agg[(size_t)rb * DIM + (k0 - 128)];
        }
        #pragma unroll
        for (int ct = 0; ct < 8; ++ct) {
            v8bf b = ld8<F32>(Wu1, (size_t)(ct * 16 + l15) * 256 + k0);
            acc[0][ct] = MFMA(a0, b, acc[0][ct]);
            acc[1][ct] = MFMA(a1, b, acc[1][ct]);
        }
    }
    #pragma unroll
    for (int ct = 0; ct < 8; ++ct) {
        float bb = lds1<F32>(bu1, ct * 16 + l15);
        int c8w = (ct << 1) | (l15 >> 3);
        #pragma unroll
        for (int i = 0; i < 2; ++i)
            #pragma unroll
            for (int r = 0; r < 4; ++r) {
                int row = i * 16 + quad * 4 + r;
                s[row * DIM + (((c8w ^ (row & 15)) << 3) | (l15 & 7))] =
                    (bf16)fmaxf(acc[i][ct][r] + bb, 0.f);
            }
    }
    // layer 2: K = 128
    f32x4 acc2[2][8] = {};
    #pragma unroll
    for (int kt = 0; kt < 4; ++kt) {
        int k0 = kt * 32 + quad * 8;
        int c8 = kt * 4 + quad;
        v8bf a0 = *(const v8bf*)&s[l15 * DIM + ((c8 ^ l15) << 3)];
        v8bf a1 = *(const v8bf*)&s[(16 + l15) * DIM + ((c8 ^ l15) << 3)];
        #pragma unroll
        for (int ct = 0; ct < 8; ++ct) {
            v8bf b = ld8<F32>(Wu2, (size_t)(ct * 16 + l15) * DIM + k0);
            acc2[0][ct] = MFMA(a0, b, acc2[0][ct]);
            acc2[1][ct] = MFMA(a1, b, acc2[1][ct]);
        }
    }

    // epilogue
    float bu2c[8], gc[8], bc[8];
    #pragma unroll
    for (int ct = 0; ct < 8; ++ct) {
        int col = ct * 16 + l15;
        bu2c[ct] = lds1<F32>(bu2, col);
        gc[ct]   = lds1<F32>(gam, col);
        bc[ct]   = lds1<F32>(bet, col);
    }
    #pragma unroll
    for (int i = 0; i < 2; ++i) {
        #pragma unroll
        for (int r = 0; r < 4; ++r) {
            int grow = row0 + i * 16 + quad * 4 + r;
            size_t growc = (size_t)min(grow, N_NODES - 1);
            float u[8], s1 = 0.f, s2 = 0.f;
            #pragma unroll
            for (int ct = 0; ct < 8; ++ct) {
                float v = acc2[i][ct][r] + bu2c[ct]
                        + lds1<F32>(x, growc * DIM + ct * 16 + l15);
                u[ct] = v; s1 += v; s2 += v * v;
            }
            #pragma unroll
            for (int off = 1; off < 16; off <<= 1) {
                s1 += __shfl_xor(s1, off);
                s2 += __shfl_xor(s2, off);
            }
            float mean = s1 * (1.f / 128.f);
            float var  = s2 * (1.f / 128.f) - mean * mean;
            float rstd = rsqrtf(var + 1e-5f);
            if (grow < N_NODES) {
                #pragma unroll
                for (int ct = 0; ct < 8; ++ct) {
                    float v = (u[ct] - mean) * rstd * gc[ct] + bc[ct];
                    if constexpr (F32) ((float*)out)[(size_t)grow * DIM + ct * 16 + l15] = v;
                    else               ((bf16*)out)[(size_t)grow * DIM + ct * 16 + l15] = (bf16)v;
                }
            }
        }
    }
}

__global__ __launch_bounds__(256) void update_kernel(
    const void* __restrict__ x, const void* __restrict__ ei,
    const bf16* __restrict__ agg,
    const void* Wu1, const void* bu1, const void* Wu2, const void* bu2,
    const void* gam, const void* bet, void* __restrict__ out)
{
    __shared__ __align__(16) bf16 sc[4][32 * DIM];   // 32 KB
    __shared__ int sf[2];
    int f32m, i64m;
    detect(x, ei, sf, f32m, i64m);
    if (f32m) update_body<true>(x, agg, Wu1, bu1, Wu2, bu2, gam, bet, out,
                                sc[threadIdx.x >> 6], blockIdx.x);
    else      update_body<false>(x, agg, Wu1, bu1, Wu2, bu2, gam, bet, out,
                                 sc[threadIdx.x >> 6], blockIdx.x);
}

// ---------------------------------------------------------------------------
extern "C" void kernel_launch(void* const* d_in, const int* in_sizes, int n_in,
                              void* d_out, int out_size, void* d_ws, size_t ws_size,
                              hipStream_t stream) {
    const void* x  = d_in[0];
    const void* ei = d_in[1];

    char* ws = (char*)d_ws;
    size_t off = 0;
    auto alloc = [&](size_t bytes) {
        void* p = ws + off;
        off += (bytes + 255) & ~(size_t)255;
        return p;
    };
    bf16* y   = (bf16*)alloc((size_t)N_NODES * DIM * sizeof(bf16));          // 10.24 MB
    bf16* agg = (bf16*)alloc((size_t)N_NODES * DIM * sizeof(bf16));          // 10.24 MB
    int*  cnt = (int*)alloc(N_NODES * sizeof(int));                          // 160 KB
    unsigned short* padded =
        (unsigned short*)alloc((size_t)N_NODES * PAD * sizeof(unsigned short)); // 5.12 MB

    hipMemsetAsync(cnt, 0, N_NODES * sizeof(int), stream);

    fat_kernel<<<FAT_BLOCKS, 256, 0, stream>>>(
        x, ei, d_in[2], d_in[3], d_in[4], d_in[5], cnt, padded, y);
    agg_kernel<<<N_NODES / 4, 256, 0, stream>>>(y, padded, cnt, agg);
    update_kernel<<<NBLK_MSG, 256, 0, stream>>>(
        x, ei, agg, d_in[6], d_in[7], d_in[8], d_in[9], d_in[10], d_in[11], d_out);
}

// Round 8
// 245.569 us; speedup vs baseline: 1.0211x; 1.0211x over previous
//
#include <hip/hip_runtime.h>

#define N_NODES 40000
#define N_EDGES 640000
#define DIM 128
#define PAD 64            // deg ~ Poisson(16), P(>64) ~ 1e-18
#define NBLK_GEMM 313     // ceil(40000/128): 4 waves/block, 32 rows/wave
#define SCAT_ILP 4
#define SCAT_BLOCKS (N_EDGES / (256 * SCAT_ILP))   // 625

typedef __bf16 bf16;
typedef __bf16 v8bf __attribute__((ext_vector_type(8)));
typedef float f32x4 __attribute__((ext_vector_type(4)));

#define MFMA(a, b, c) __builtin_amdgcn_mfma_f32_16x16x32_bf16(a, b, c, 0, 0, 0)

// ---------------------------------------------------------------------------
// Per-block redundant dtype detection (8 KB of L2-hot reads, no global
// round-trip). f32 low halfwords are random mantissa bits (exp>=0xC0 w.p.
// 25%/sample); bf16 activations never reach exp 0x83. int64 indices < 40000
// have all-zero high words.
// ---------------------------------------------------------------------------
__device__ __forceinline__ void detect(const void* x, const void* ei,
                                       int* sf, int& f32m, int& i64m) {
    const int tid = threadIdx.x;
    if (tid == 0) { sf[0] = 0; sf[1] = 0; }
    __syncthreads();
    const unsigned short* xh = (const unsigned short*)x;
    const unsigned int* eiw = (const unsigned int*)ei;
    int isf32 = 0; unsigned int orhi = 0;
    #pragma unroll
    for (int j = 0; j < 4; ++j) {
        unsigned short h = xh[2 * (tid + 256 * j)];
        if (((h >> 7) & 0xFF) >= 0xC0) isf32 = 1;
        orhi |= eiw[2 * (tid + 256 * j) + 1];
    }
    if (isf32) atomicOr(&sf[0], 1);
    if (orhi)  atomicOr(&sf[1], 1);
    __syncthreads();
    f32m = sf[0];
    i64m = sf[1] ? 0 : 1;
}

// load 8 consecutive "float" elements as bf16 fragment (cvt in reg if f32)
template<bool F32>
__device__ __forceinline__ v8bf ld8(const void* p, size_t idx) {
    if constexpr (F32) {
        const float* f = (const float*)p + idx;
        float4 a = *(const float4*)f, b = *(const float4*)(f + 4);
        v8bf r;
        r[0] = (bf16)a.x; r[1] = (bf16)a.y; r[2] = (bf16)a.z; r[3] = (bf16)a.w;
        r[4] = (bf16)b.x; r[5] = (bf16)b.y; r[6] = (bf16)b.z; r[7] = (bf16)b.w;
        return r;
    } else {
        return *(const v8bf*)((const bf16*)p + idx);
    }
}

template<bool F32>
__device__ __forceinline__ float lds1(const void* p, size_t i) {
    if constexpr (F32) return ((const float*)p)[i];
    else               return (float)((const bf16*)p)[i];
}

// ---------------------------------------------------------------------------
// Scatter: one-pass padded-bucket build. 0 LDS -> high occupancy; 4 grid-
// strided edges per thread = 4 independent atomic/store chains in flight.
// ---------------------------------------------------------------------------
__global__ __launch_bounds__(256) void scatter_kernel(
    const void* __restrict__ x, const void* __restrict__ ei,
    int* __restrict__ cnt, unsigned short* __restrict__ padded)
{
    __shared__ int sf[2];
    int f32m, i64m;
    detect(x, ei, sf, f32m, i64m);

    const int base = blockIdx.x * 256 + threadIdx.x;
    const int stride = SCAT_BLOCKS * 256;      // 160000
    int s[SCAT_ILP], d[SCAT_ILP];
    if (i64m) {
        const long long* p = (const long long*)ei;
        #pragma unroll
        for (int j = 0; j < SCAT_ILP; ++j) {
            int e = base + j * stride;
            s[j] = (int)p[e]; d[j] = (int)p[N_EDGES + e];
        }
    } else {
        const int* p = (const int*)ei;
        #pragma unroll
        for (int j = 0; j < SCAT_ILP; ++j) {
            int e = base + j * stride;
            s[j] = p[e]; d[j] = p[N_EDGES + e];
        }
    }
    int pos[SCAT_ILP];
    #pragma unroll
    for (int j = 0; j < SCAT_ILP; ++j) pos[j] = atomicAdd(&cnt[d[j]], 1);
    #pragma unroll
    for (int j = 0; j < SCAT_ILP; ++j)
        if (pos[j] < PAD) padded[(d[j] << 6) + pos[j]] = (unsigned short)s[j];
}

// ---------------------------------------------------------------------------
// msg: y = relu(x@Wm1^T+bm1)@Wm2^T+bm2 for 128 rows/block. Per-wave LDS-free
// GEMM: A/B fragments straight from global (L2-resident weights), f32->bf16
// in registers; 8 KB/wave XOR-swizzled scratch for the h1 C-layout ->
// A-layout transpose (2-way max bank aliasing = free):
//   off(row,col) = row*128 + (((col>>3) ^ (row&15))<<3) + (col&7)
// ---------------------------------------------------------------------------
template<bool F32>
__device__ void msg_body(const void* x, const void* Wm1, const void* bm1,
                         const void* Wm2, const void* bm2,
                         bf16* __restrict__ y, bf16* s, int mb) {
    const int wave = threadIdx.x >> 6, lane = threadIdx.x & 63;
    const int l15 = lane & 15, quad = lane >> 4;
    const int row0 = (mb * 4 + wave) * 32;
    const int ra = min(row0 + l15, N_NODES - 1);
    const int rb = min(row0 + 16 + l15, N_NODES - 1);

    f32x4 acc[2][8] = {};
    #pragma unroll
    for (int kt = 0; kt < 4; ++kt) {
        int k0 = kt * 32 + quad * 8;
        v8bf a0 = ld8<F32>(x, (size_t)ra * DIM + k0);
        v8bf a1 = ld8<F32>(x, (size_t)rb * DIM + k0);
        #pragma unroll
        for (int ct = 0; ct < 8; ++ct) {
            v8bf b = ld8<F32>(Wm1, (size_t)(ct * 16 + l15) * DIM + k0);
            acc[0][ct] = MFMA(a0, b, acc[0][ct]);
            acc[1][ct] = MFMA(a1, b, acc[1][ct]);
        }
    }
    #pragma unroll
    for (int ct = 0; ct < 8; ++ct) {
        float bb = lds1<F32>(bm1, ct * 16 + l15);
        int c8w = (ct << 1) | (l15 >> 3);
        #pragma unroll
        for (int i = 0; i < 2; ++i)
            #pragma unroll
            for (int r = 0; r < 4; ++r) {
                int row = i * 16 + quad * 4 + r;
                s[row * DIM + (((c8w ^ (row & 15)) << 3) | (l15 & 7))] =
                    (bf16)fmaxf(acc[i][ct][r] + bb, 0.f);
            }
    }
    f32x4 acc2[2][8] = {};
    #pragma unroll
    for (int kt = 0; kt < 4; ++kt) {
        int k0 = kt * 32 + quad * 8;
        int c8 = kt * 4 + quad;
        v8bf a0 = *(const v8bf*)&s[l15 * DIM + ((c8 ^ l15) << 3)];
        v8bf a1 = *(const v8bf*)&s[(16 + l15) * DIM + ((c8 ^ l15) << 3)];
        #pragma unroll
        for (int ct = 0; ct < 8; ++ct) {
            v8bf b = ld8<F32>(Wm2, (size_t)(ct * 16 + l15) * DIM + k0);
            acc2[0][ct] = MFMA(a0, b, acc2[0][ct]);
            acc2[1][ct] = MFMA(a1, b, acc2[1][ct]);
        }
    }
    #pragma unroll
    for (int ct = 0; ct < 8; ++ct) {
        float bb = lds1<F32>(bm2, ct * 16 + l15);
        #pragma unroll
        for (int i = 0; i < 2; ++i)
            #pragma unroll
            for (int r = 0; r < 4; ++r) {
                int grow = row0 + i * 16 + quad * 4 + r;
                if (grow < N_NODES)
                    y[(size_t)grow * DIM + ct * 16 + l15] = (bf16)(acc2[i][ct][r] + bb);
            }
    }
}

__global__ __launch_bounds__(256) void msg_kernel(
    const void* __restrict__ x, const void* __restrict__ ei,
    const void* Wm1, const void* bm1, const void* Wm2, const void* bm2,
    bf16* __restrict__ y)
{
    __shared__ __align__(16) bf16 sc[4][32 * DIM];   // 32 KB
    __shared__ int sf[2];
    int f32m, i64m;
    detect(x, ei, sf, f32m, i64m);
    if (f32m) msg_body<true>(x, Wm1, bm1, Wm2, bm2, y, sc[threadIdx.x >> 6], blockIdx.x);
    else      msg_body<false>(x, Wm1, bm1, Wm2, bm2, y, sc[threadIdx.x >> 6], blockIdx.x);
}

// ---------------------------------------------------------------------------
// Per-node gather-mean over padded u16 buckets, wave-per-node; 4 slots x
// dual stream = 8 row-loads in flight per wave iteration.
// ---------------------------------------------------------------------------
__device__ __forceinline__ void accum8(float* s, uint4 v) {
    v8bf b = __builtin_bit_cast(v8bf, v);
    #pragma unroll
    for (int j = 0; j < 8; ++j) s[j] += (float)b[j];
}

__global__ __launch_bounds__(256) void agg_kernel(const bf16* __restrict__ y,
                                                  const unsigned short* __restrict__ padded,
                                                  const int* __restrict__ cnt,
                                                  bf16* __restrict__ agg) {
    const int node = (blockIdx.x << 2) + (threadIdx.x >> 6);
    const int lane = threadIdx.x & 63;
    const int slot = lane >> 4, c16 = lane & 15;
    const int c = min(cnt[node], PAD);
    const int beg = node << 6;
    const int end = beg + c;
    const uint4* yv = (const uint4*)y;

    float s0[8] = {}, s1[8] = {};
    int e = beg + slot;
    for (; e + 4 < end; e += 8) {
        int i0 = padded[e], i1 = padded[e + 4];
        uint4 v0 = yv[(size_t)i0 * 16 + c16];
        uint4 v1 = yv[(size_t)i1 * 16 + c16];
        accum8(s0, v0);
        accum8(s1, v1);
    }
    if (e < end) accum8(s0, yv[(size_t)padded[e] * 16 + c16]);

    float inv = 1.f / (float)(c > 0 ? c : 1);
    v8bf o;
    #pragma unroll
    for (int j = 0; j < 8; ++j) {
        float v = s0[j] + s1[j];
        v += __shfl_xor(v, 16);
        v += __shfl_xor(v, 32);
        o[j] = (bf16)(v * inv);
    }
    if (slot == 0)
        ((uint4*)agg)[(size_t)node * 16 + c16] = __builtin_bit_cast(uint4, o);
}

// ---------------------------------------------------------------------------
// update: u = relu([x|agg]@Wu1^T+bu1)@Wu2^T+bu2; h=u+x; LN(h)*gamma+beta.
// Direct global reads (f32 cvt in reg); LN via 16-lane quad shuffle reduce.
// ---------------------------------------------------------------------------
template<bool F32>
__device__ void update_body(const void* x, const bf16* __restrict__ agg,
                            const void* Wu1, const void* bu1,
                            const void* Wu2, const void* bu2,
                            const void* gam, const void* bet,
                            void* __restrict__ out, bf16* s, int ub) {
    const int wave = threadIdx.x >> 6, lane = threadIdx.x & 63;
    const int l15 = lane & 15, quad = lane >> 4;
    const int row0 = (ub * 4 + wave) * 32;
    const int ra = min(row0 + l15, N_NODES - 1);
    const int rb = min(row0 + 16 + l15, N_NODES - 1);

    f32x4 acc[2][8] = {};
    #pragma unroll
    for (int kt = 0; kt < 8; ++kt) {
        int k0 = kt * 32 + quad * 8;
        v8bf a0, a1;
        if (kt < 4) {
            a0 = ld8<F32>(x, (size_t)ra * DIM + k0);
            a1 = ld8<F32>(x, (size_t)rb * DIM + k0);
        } else {
            a0 = *(const v8bf*)&agg[(size_t)ra * DIM + (k0 - 128)];
            a1 = *(const v8bf*)&agg[(size_t)rb * DIM + (k0 - 128)];
        }
        #pragma unroll
        for (int ct = 0; ct < 8; ++ct) {
            v8bf b = ld8<F32>(Wu1, (size_t)(ct * 16 + l15) * 256 + k0);
            acc[0][ct] = MFMA(a0, b, acc[0][ct]);
            acc[1][ct] = MFMA(a1, b, acc[1][ct]);
        }
    }
    #pragma unroll
    for (int ct = 0; ct < 8; ++ct) {
        float bb = lds1<F32>(bu1, ct * 16 + l15);
        int c8w = (ct << 1) | (l15 >> 3);
        #pragma unroll
        for (int i = 0; i < 2; ++i)
            #pragma unroll
            for (int r = 0; r < 4; ++r) {
                int row = i * 16 + quad * 4 + r;
                s[row * DIM + (((c8w ^ (row & 15)) << 3) | (l15 & 7))] =
                    (bf16)fmaxf(acc[i][ct][r] + bb, 0.f);
            }
    }
    f32x4 acc2[2][8] = {};
    #pragma unroll
    for (int kt = 0; kt < 4; ++kt) {
        int k0 = kt * 32 + quad * 8;
        int c8 = kt * 4 + quad;
        v8bf a0 = *(const v8bf*)&s[l15 * DIM + ((c8 ^ l15) << 3)];
        v8bf a1 = *(const v8bf*)&s[(16 + l15) * DIM + ((c8 ^ l15) << 3)];
        #pragma unroll
        for (int ct = 0; ct < 8; ++ct) {
            v8bf b = ld8<F32>(Wu2, (size_t)(ct * 16 + l15) * DIM + k0);
            acc2[0][ct] = MFMA(a0, b, acc2[0][ct]);
            acc2[1][ct] = MFMA(a1, b, acc2[1][ct]);
        }
    }

    float bu2c[8], gc[8], bc[8];
    #pragma unroll
    for (int ct = 0; ct < 8; ++ct) {
        int col = ct * 16 + l15;
        bu2c[ct] = lds1<F32>(bu2, col);
        gc[ct]   = lds1<F32>(gam, col);
        bc[ct]   = lds1<F32>(bet, col);
    }
    #pragma unroll
    for (int i = 0; i < 2; ++i) {
        #pragma unroll
        for (int r = 0; r < 4; ++r) {
            int grow = row0 + i * 16 + quad * 4 + r;
            size_t growc = (size_t)min(grow, N_NODES - 1);
            float u[8], s1 = 0.f, s2 = 0.f;
            #pragma unroll
            for (int ct = 0; ct < 8; ++ct) {
                float v = acc2[i][ct][r] + bu2c[ct]
                        + lds1<F32>(x, growc * DIM + ct * 16 + l15);
                u[ct] = v; s1 += v; s2 += v * v;
            }
            #pragma unroll
            for (int off = 1; off < 16; off <<= 1) {
                s1 += __shfl_xor(s1, off);
                s2 += __shfl_xor(s2, off);
            }
            float mean = s1 * (1.f / 128.f);
            float var  = s2 * (1.f / 128.f) - mean * mean;
            float rstd = rsqrtf(var + 1e-5f);
            if (grow < N_NODES) {
                #pragma unroll
                for (int ct = 0; ct < 8; ++ct) {
                    float v = (u[ct] - mean) * rstd * gc[ct] + bc[ct];
                    if constexpr (F32) ((float*)out)[(size_t)grow * DIM + ct * 16 + l15] = v;
                    else               ((bf16*)out)[(size_t)grow * DIM + ct * 16 + l15] = (bf16)v;
                }
            }
        }
    }
}

__global__ __launch_bounds__(256) void update_kernel(
    const void* __restrict__ x, const void* __restrict__ ei,
    const bf16* __restrict__ agg,
    const void* Wu1, const void* bu1, const void* Wu2, const void* bu2,
    const void* gam, const void* bet, void* __restrict__ out)
{
    __shared__ __align__(16) bf16 sc[4][32 * DIM];   // 32 KB
    __shared__ int sf[2];
    int f32m, i64m;
    detect(x, ei, sf, f32m, i64m);
    if (f32m) update_body<true>(x, agg, Wu1, bu1, Wu2, bu2, gam, bet, out,
                                sc[threadIdx.x >> 6], blockIdx.x);
    else      update_body<false>(x, agg, Wu1, bu1, Wu2, bu2, gam, bet, out,
                                 sc[threadIdx.x >> 6], blockIdx.x);
}

// ---------------------------------------------------------------------------
extern "C" void kernel_launch(void* const* d_in, const int* in_sizes, int n_in,
                              void* d_out, int out_size, void* d_ws, size_t ws_size,
                              hipStream_t stream) {
    const void* x  = d_in[0];
    const void* ei = d_in[1];

    char* ws = (char*)d_ws;
    size_t off = 0;
    auto alloc = [&](size_t bytes) {
        void* p = ws + off;
        off += (bytes + 255) & ~(size_t)255;
        return p;
    };
    bf16* y   = (bf16*)alloc((size_t)N_NODES * DIM * sizeof(bf16));          // 10.24 MB
    bf16* agg = (bf16*)alloc((size_t)N_NODES * DIM * sizeof(bf16));          // 10.24 MB
    int*  cnt = (int*)alloc(N_NODES * sizeof(int));                          // 160 KB
    unsigned short* padded =
        (unsigned short*)alloc((size_t)N_NODES * PAD * sizeof(unsigned short)); // 5.12 MB

    hipMemsetAsync(cnt, 0, N_NODES * sizeof(int), stream);

    scatter_kernel<<<SCAT_BLOCKS, 256, 0, stream>>>(x, ei, cnt, padded);
    msg_kernel<<<NBLK_GEMM, 256, 0, stream>>>(
        x, ei, d_in[2], d_in[3], d_in[4], d_in[5], y);
    agg_kernel<<<N_NODES / 4, 256, 0, stream>>>(y, padded, cnt, agg);
    update_kernel<<<NBLK_GEMM, 256, 0, stream>>>(
        x, ei, agg, d_in[6], d_in[7], d_in[8], d_in[9], d_in[10], d_in[11], d_out);
}

// Round 9
// 227.514 us; speedup vs baseline: 1.1021x; 1.0794x over previous
//
#include <hip/hip_runtime.h>

#define N_NODES 40000
#define N_EDGES 640000
#define DIM 128
#define PAD 64            // deg ~ Poisson(16), P(>64) ~ 1e-18
#define NBLK_GEMM 625     // 40000 rows / 16 rows/wave / 4 waves/block (exact)
#define SCAT_ILP 4
#define SCAT_BLOCKS (N_EDGES / (256 * SCAT_ILP))   // 625

typedef __bf16 bf16;
typedef __bf16 v8bf __attribute__((ext_vector_type(8)));
typedef __bf16 v4bf __attribute__((ext_vector_type(4)));
typedef float f32x4 __attribute__((ext_vector_type(4)));

#define MFMA(a, b, c) __builtin_amdgcn_mfma_f32_16x16x32_bf16(a, b, c, 0, 0, 0)

// bf16 parameter pack offsets (elements)
#define OFF_WM1 0
#define OFF_BM1 16384
#define OFF_WM2 16512
#define OFF_BM2 32896
#define OFF_WU1 33024
#define OFF_BU1 65792
#define OFF_WU2 65920
#define OFF_BU2 82304
#define OFF_GAM 82432
#define OFF_BET 82560
#define NPARAM  82688

// ---------------------------------------------------------------------------
// Per-block redundant dtype detection (8 KB of L2-hot reads). f32 low
// halfwords are random mantissa bits (exp>=0xC0 w.p. 25%/sample); bf16
// activations never reach exp 0x83. int64 indices < 40000 have zero hi words.
// ---------------------------------------------------------------------------
__device__ __forceinline__ void detect(const void* x, const void* ei,
                                       int* sf, int& f32m, int& i64m) {
    const int tid = threadIdx.x;
    if (tid == 0) { sf[0] = 0; sf[1] = 0; }
    __syncthreads();
    const unsigned short* xh = (const unsigned short*)x;
    const unsigned int* eiw = (const unsigned int*)ei;
    int isf32 = 0; unsigned int orhi = 0;
    #pragma unroll
    for (int j = 0; j < 4; ++j) {
        unsigned short h = xh[2 * (tid + 256 * j)];
        if (((h >> 7) & 0xFF) >= 0xC0) isf32 = 1;
        orhi |= eiw[2 * (tid + 256 * j) + 1];
    }
    if (isf32) atomicOr(&sf[0], 1);
    if (orhi)  atomicOr(&sf[1], 1);
    __syncthreads();
    f32m = sf[0];
    i64m = sf[1] ? 0 : 1;
}

// ---------------------------------------------------------------------------
// Scatter + convert kernel (0 LDS except tiny sf -> high occupancy).
// Roles per thread: (a) 4 grid-strided edges -> padded u16 buckets (ILP-4
// atomic chains); (b) grid-stride convert x -> xb bf16; (c) params -> wp.
// The streaming converts overlap the scatter's atomic latency.
// ---------------------------------------------------------------------------
__global__ __launch_bounds__(256) void scatter_kernel(
    const void* __restrict__ x, const void* __restrict__ ei,
    const void* p0, const void* p1, const void* p2, const void* p3,
    const void* p4, const void* p5, const void* p6, const void* p7,
    const void* p8, const void* p9,
    int* __restrict__ cnt, unsigned short* __restrict__ padded,
    bf16* __restrict__ xb, bf16* __restrict__ wp, int* __restrict__ flags)
{
    __shared__ int sf[2];
    int f32m, i64m;
    detect(x, ei, sf, f32m, i64m);
    const int gid = blockIdx.x * 256 + threadIdx.x;
    const int gstride = SCAT_BLOCKS * 256;     // 160000
    if (gid == 0) { flags[0] = f32m; flags[1] = i64m; }

    // ---- edge loads (issue early) ----
    int s[SCAT_ILP], d[SCAT_ILP];
    if (i64m) {
        const long long* p = (const long long*)ei;
        #pragma unroll
        for (int j = 0; j < SCAT_ILP; ++j) {
            int e = gid + j * gstride;
            s[j] = (int)p[e]; d[j] = (int)p[N_EDGES + e];
        }
    } else {
        const int* p = (const int*)ei;
        #pragma unroll
        for (int j = 0; j < SCAT_ILP; ++j) {
            int e = gid + j * gstride;
            s[j] = p[e]; d[j] = p[N_EDGES + e];
        }
    }
    int pos[SCAT_ILP];
    #pragma unroll
    for (int j = 0; j < SCAT_ILP; ++j) pos[j] = atomicAdd(&cnt[d[j]], 1);
    #pragma unroll
    for (int j = 0; j < SCAT_ILP; ++j)
        if (pos[j] < PAD) padded[(d[j] << 6) + pos[j]] = (unsigned short)s[j];

    // ---- convert x -> xb ----
    const int NT = N_NODES * DIM;
    if (f32m) {
        const float4* g = (const float4*)x;
        v4bf* o = (v4bf*)xb;
        for (int i = gid; i < NT / 4; i += gstride) {
            float4 v = g[i];
            v4bf t; t[0] = (bf16)v.x; t[1] = (bf16)v.y; t[2] = (bf16)v.z; t[3] = (bf16)v.w;
            o[i] = t;
        }
    } else {
        const uint4* g = (const uint4*)x;
        uint4* o = (uint4*)xb;
        for (int i = gid; i < NT / 8; i += gstride) o[i] = g[i];
    }
    // ---- convert params -> wp ----
    for (int i = gid; i < NPARAM; i += gstride) {
        const void* src; int base;
        if      (i < OFF_BM1) { src = p0; base = OFF_WM1; }
        else if (i < OFF_WM2) { src = p1; base = OFF_BM1; }
        else if (i < OFF_BM2) { src = p2; base = OFF_WM2; }
        else if (i < OFF_WU1) { src = p3; base = OFF_BM2; }
        else if (i < OFF_BU1) { src = p4; base = OFF_WU1; }
        else if (i < OFF_WU2) { src = p5; base = OFF_BU1; }
        else if (i < OFF_BU2) { src = p6; base = OFF_WU2; }
        else if (i < OFF_GAM) { src = p7; base = OFF_BU2; }
        else if (i < OFF_BET) { src = p8; base = OFF_GAM; }
        else                  { src = p9; base = OFF_BET; }
        int j = i - base;
        float v = f32m ? ((const float*)src)[j] : (float)((const bf16*)src)[j];
        wp[i] = (bf16)v;
    }
}

// ---------------------------------------------------------------------------
// Per-wave LDS-free GEMM, 16 rows x 128 cols per wave (2500 waves -> 2.4
// waves/SIMD). A/B fragments read straight from global bf16 (L2-resident
// weights). 4 KB/wave XOR-swizzled scratch for the h1 C-layout -> A-layout
// transpose (2-way max bank aliasing = free):
//   off(row,col) = row*128 + (((col>>3) ^ row)<<3) + (col&7),  row in [0,16)
// ---------------------------------------------------------------------------
__global__ __launch_bounds__(256) void msg_kernel(const bf16* __restrict__ xb,
                                                  const bf16* __restrict__ wp,
                                                  bf16* __restrict__ y)
{
    __shared__ __align__(16) bf16 sc[4][16 * DIM];   // 16 KB
    const int wave = threadIdx.x >> 6, lane = threadIdx.x & 63;
    const int l15 = lane & 15, quad = lane >> 4;
    const int row0 = (blockIdx.x * 4 + wave) * 16;   // exact: 40000 = 16*2500
    bf16* s = sc[wave];
    const size_t ra = (size_t)(row0 + l15) * DIM;

    // layer 1
    f32x4 acc[8] = {};
    #pragma unroll
    for (int kt = 0; kt < 4; ++kt) {
        int k0 = kt * 32 + quad * 8;
        v8bf a0 = *(const v8bf*)&xb[ra + k0];
        #pragma unroll
        for (int ct = 0; ct < 8; ++ct) {
            v8bf b = *(const v8bf*)&wp[OFF_WM1 + (size_t)(ct * 16 + l15) * DIM + k0];
            acc[ct] = MFMA(a0, b, acc[ct]);
        }
    }
    // relu + bias -> swizzled scratch (wave-local; no barrier)
    #pragma unroll
    for (int ct = 0; ct < 8; ++ct) {
        float bb = (float)wp[OFF_BM1 + ct * 16 + l15];
        int c8w = (ct << 1) | (l15 >> 3);
        #pragma unroll
        for (int r = 0; r < 4; ++r) {
            int row = quad * 4 + r;
            s[row * DIM + (((c8w ^ row) << 3) | (l15 & 7))] =
                (bf16)fmaxf(acc[ct][r] + bb, 0.f);
        }
    }
    // layer 2
    f32x4 acc2[8] = {};
    #pragma unroll
    for (int kt = 0; kt < 4; ++kt) {
        int k0 = kt * 32 + quad * 8;
        int c8 = kt * 4 + quad;
        v8bf a0 = *(const v8bf*)&s[l15 * DIM + ((c8 ^ l15) << 3)];
        #pragma unroll
        for (int ct = 0; ct < 8; ++ct) {
            v8bf b = *(const v8bf*)&wp[OFF_WM2 + (size_t)(ct * 16 + l15) * DIM + k0];
            acc2[ct] = MFMA(a0, b, acc2[ct]);
        }
    }
    #pragma unroll
    for (int ct = 0; ct < 8; ++ct) {
        float bb = (float)wp[OFF_BM2 + ct * 16 + l15];
        #pragma unroll
        for (int r = 0; r < 4; ++r) {
            int grow = row0 + quad * 4 + r;
            y[(size_t)grow * DIM + ct * 16 + l15] = (bf16)(acc2[ct][r] + bb);
        }
    }
}

// ---------------------------------------------------------------------------
// Per-node gather-mean over padded u16 buckets, wave-per-node; 4 slots x
// dual stream = 8 row-loads in flight per wave iteration.
// ---------------------------------------------------------------------------
__device__ __forceinline__ void accum8(float* s, uint4 v) {
    v8bf b = __builtin_bit_cast(v8bf, v);
    #pragma unroll
    for (int j = 0; j < 8; ++j) s[j] += (float)b[j];
}

__global__ __launch_bounds__(256) void agg_kernel(const bf16* __restrict__ y,
                                                  const unsigned short* __restrict__ padded,
                                                  const int* __restrict__ cnt,
                                                  bf16* __restrict__ agg) {
    const int node = (blockIdx.x << 2) + (threadIdx.x >> 6);
    const int lane = threadIdx.x & 63;
    const int slot = lane >> 4, c16 = lane & 15;
    const int c = min(cnt[node], PAD);
    const int beg = node << 6;
    const int end = beg + c;
    const uint4* yv = (const uint4*)y;

    float s0[8] = {}, s1[8] = {};
    int e = beg + slot;
    for (; e + 4 < end; e += 8) {
        int i0 = padded[e], i1 = padded[e + 4];
        uint4 v0 = yv[(size_t)i0 * 16 + c16];
        uint4 v1 = yv[(size_t)i1 * 16 + c16];
        accum8(s0, v0);
        accum8(s1, v1);
    }
    if (e < end) accum8(s0, yv[(size_t)padded[e] * 16 + c16]);

    float inv = 1.f / (float)(c > 0 ? c : 1);
    v8bf o;
    #pragma unroll
    for (int j = 0; j < 8; ++j) {
        float v = s0[j] + s1[j];
        v += __shfl_xor(v, 16);
        v += __shfl_xor(v, 32);
        o[j] = (bf16)(v * inv);
    }
    if (slot == 0)
        ((uint4*)agg)[(size_t)node * 16 + c16] = __builtin_bit_cast(uint4, o);
}

// ---------------------------------------------------------------------------
// update: u = relu([x|agg]@Wu1^T+bu1)@Wu2^T+bu2; h=u+x; LN(h)*gamma+beta.
// 16 rows/wave; bf16 inputs; LN via 16-lane quad shuffle reduce. Output
// dtype from flags[0] (wave-uniform branch).
// ---------------------------------------------------------------------------
__global__ __launch_bounds__(256) void update_kernel(
    const bf16* __restrict__ xb, const bf16* __restrict__ agg,
    const bf16* __restrict__ wp, const int* __restrict__ flags,
    void* __restrict__ out)
{
    __shared__ __align__(16) bf16 sc[4][16 * DIM];   // 16 KB
    const int wave = threadIdx.x >> 6, lane = threadIdx.x & 63;
    const int l15 = lane & 15, quad = lane >> 4;
    const int row0 = (blockIdx.x * 4 + wave) * 16;
    bf16* s = sc[wave];
    const size_t ra = (size_t)(row0 + l15) * DIM;
    const int of32 = flags[0];

    // layer 1: K = 256 over [x | agg]
    f32x4 acc[8] = {};
    #pragma unroll
    for (int kt = 0; kt < 8; ++kt) {
        int k0 = kt * 32 + quad * 8;
        v8bf a0 = (kt < 4) ? *(const v8bf*)&xb[ra + k0]
                           : *(const v8bf*)&agg[ra + (k0 - 128)];
        #pragma unroll
        for (int ct = 0; ct < 8; ++ct) {
            v8bf b = *(const v8bf*)&wp[OFF_WU1 + (size_t)(ct * 16 + l15) * 256 + k0];
            acc[ct] = MFMA(a0, b, acc[ct]);
        }
    }
    #pragma unroll
    for (int ct = 0; ct < 8; ++ct) {
        float bb = (float)wp[OFF_BU1 + ct * 16 + l15];
        int c8w = (ct << 1) | (l15 >> 3);
        #pragma unroll
        for (int r = 0; r < 4; ++r) {
            int row = quad * 4 + r;
            s[row * DIM + (((c8w ^ row) << 3) | (l15 & 7))] =
                (bf16)fmaxf(acc[ct][r] + bb, 0.f);
        }
    }
    // layer 2: K = 128
    f32x4 acc2[8] = {};
    #pragma unroll
    for (int kt = 0; kt < 4; ++kt) {
        int k0 = kt * 32 + quad * 8;
        int c8 = kt * 4 + quad;
        v8bf a0 = *(const v8bf*)&s[l15 * DIM + ((c8 ^ l15) << 3)];
        #pragma unroll
        for (int ct = 0; ct < 8; ++ct) {
            v8bf b = *(const v8bf*)&wp[OFF_WU2 + (size_t)(ct * 16 + l15) * DIM + k0];
            acc2[ct] = MFMA(a0, b, acc2[ct]);
        }
    }

    // epilogue: +bu2, +x residual, LayerNorm, store
    float bu2c[8], gc[8], bc[8];
    #pragma unroll
    for (int ct = 0; ct < 8; ++ct) {
        int col = ct * 16 + l15;
        bu2c[ct] = (float)wp[OFF_BU2 + col];
        gc[ct]   = (float)wp[OFF_GAM + col];
        bc[ct]   = (float)wp[OFF_BET + col];
    }
    #pragma unroll
    for (int r = 0; r < 4; ++r) {
        int grow = row0 + quad * 4 + r;
        float u[8], s1 = 0.f, s2 = 0.f;
        #pragma unroll
        for (int ct = 0; ct < 8; ++ct) {
            float v = acc2[ct][r] + bu2c[ct]
                    + (float)xb[(size_t)grow * DIM + ct * 16 + l15];
            u[ct] = v; s1 += v; s2 += v * v;
        }
        #pragma unroll
        for (int off = 1; off < 16; off <<= 1) {
            s1 += __shfl_xor(s1, off);
            s2 += __shfl_xor(s2, off);
        }
        float mean = s1 * (1.f / 128.f);
        float var  = s2 * (1.f / 128.f) - mean * mean;
        float rstd = rsqrtf(var + 1e-5f);
        if (of32) {
            #pragma unroll
            for (int ct = 0; ct < 8; ++ct)
                ((float*)out)[(size_t)grow * DIM + ct * 16 + l15] =
                    (u[ct] - mean) * rstd * gc[ct] + bc[ct];
        } else {
            #pragma unroll
            for (int ct = 0; ct < 8; ++ct)
                ((bf16*)out)[(size_t)grow * DIM + ct * 16 + l15] =
                    (bf16)((u[ct] - mean) * rstd * gc[ct] + bc[ct]);
        }
    }
}

// ---------------------------------------------------------------------------
extern "C" void kernel_launch(void* const* d_in, const int* in_sizes, int n_in,
                              void* d_out, int out_size, void* d_ws, size_t ws_size,
                              hipStream_t stream) {
    const void* x  = d_in[0];
    const void* ei = d_in[1];

    char* ws = (char*)d_ws;
    size_t off = 0;
    auto alloc = [&](size_t bytes) {
        void* p = ws + off;
        off += (bytes + 255) & ~(size_t)255;
        return p;
    };
    bf16* y   = (bf16*)alloc((size_t)N_NODES * DIM * sizeof(bf16));          // 10.24 MB
    bf16* agg = (bf16*)alloc((size_t)N_NODES * DIM * sizeof(bf16));          // 10.24 MB
    bf16* xb  = (bf16*)alloc((size_t)N_NODES * DIM * sizeof(bf16));          // 10.24 MB
    bf16* wp  = (bf16*)alloc((size_t)NPARAM * sizeof(bf16));                 // 165 KB
    int*  cnt = (int*)alloc(N_NODES * sizeof(int));                          // 160 KB
    unsigned short* padded =
        (unsigned short*)alloc((size_t)N_NODES * PAD * sizeof(unsigned short)); // 5.12 MB
    int* flags = (int*)alloc(256);

    hipMemsetAsync(cnt, 0, N_NODES * sizeof(int), stream);

    scatter_kernel<<<SCAT_BLOCKS, 256, 0, stream>>>(
        x, ei, d_in[2], d_in[3], d_in[4], d_in[5], d_in[6], d_in[7],
        d_in[8], d_in[9], d_in[10], d_in[11], cnt, padded, xb, wp, flags);
    msg_kernel<<<NBLK_GEMM, 256, 0, stream>>>(xb, wp, y);
    agg_kernel<<<N_NODES / 4, 256, 0, stream>>>(y, padded, cnt, agg);
    update_kernel<<<NBLK_GEMM, 256, 0, stream>>>(xb, agg, wp, flags, d_out);
}